// Round 4
// baseline (264.891 us; speedup 1.0000x reference)
//
#include <hip/hip_runtime.h>

typedef __attribute__((ext_vector_type(8))) short short8;
typedef __attribute__((ext_vector_type(4))) float floatx4;

#define TOKENS 2048
#define IN_F   4096
#define OUT_F  4096
#define NITER  20

#define INV_2PI 0.15915494309189535f
#define TWO_PI  6.283185307179586f

// round-to-nearest-even f32 -> bf16 bits
__device__ __forceinline__ unsigned short f2bf(float f) {
    unsigned int u = __builtin_bit_cast(unsigned int, f);
    u += 0x7fffu + ((u >> 16) & 1u);
    return (unsigned short)(u >> 16);
}

// ---------------------------------------------------------------------------
// sin(2*pi*v) for arbitrary v, pure VALU (no TRANS pipe).
// Round-3 post-mortem: non-gemm residual is a stable ~132-138us across all
// rounds while transcribe's roofline is ~25-40us -> prime suspect is
// v_sin_f32 throughput (336M sins; residual implies ~1 sin/cyc/SIMD).
// Replace with RNE range reduction + odd degree-15 Taylor of sin(2*pi*t),
// t in [-0.5,0.5]: trunc error <= 8e-7 abs, far below the bf16 output
// quantization (absmax 0.125 band) that already passes.
// 11 VALU ops/sin (rint, sub, mul, 7 fma, mul) — packable to v_pk_fma_f32.
// ---------------------------------------------------------------------------
__device__ __forceinline__ float sin2pi(float v) {
    float t = v - __builtin_rintf(v);      // [-0.5, 0.5], exact
    float s = t * t;
    float p = -0.7181223f;                 // -(2pi)^15/15!
    p = __builtin_fmaf(p, s,   3.8199968f);   // +(2pi)^13/13!
    p = __builtin_fmaf(p, s, -15.0946800f);   // -(2pi)^11/11!
    p = __builtin_fmaf(p, s,  42.0587500f);   // +(2pi)^9/9!
    p = __builtin_fmaf(p, s, -76.7058520f);   // -(2pi)^7/7!
    p = __builtin_fmaf(p, s,  81.6052490f);   // +(2pi)^5/5!
    p = __builtin_fmaf(p, s, -41.3417020f);   // -(2pi)^3/3!
    p = __builtin_fmaf(p, s,   6.2831853f);   // +(2pi)
    return t * p;
}

// one fractal step in REVOLUTION units: v' = a*v + (b/2pi)*sin(2pi*v)
__device__ __forceinline__ void step4(float4& v, float a, float bc) {
    v.x = __builtin_fmaf(bc, sin2pi(v.x), a * v.x);
    v.y = __builtin_fmaf(bc, sin2pi(v.y), a * v.y);
    v.z = __builtin_fmaf(bc, sin2pi(v.z), a * v.z);
    v.w = __builtin_fmaf(bc, sin2pi(v.w), a * v.w);
}

#define WBLOCKS (OUT_F * IN_F / 8 / 256)   // 8192
#define XBLOCKS (TOKENS * IN_F / 8 / 256)  // 4096

// Fused: blocks [0,8192) transcribe seed->w_bf (20 iters); [8192,12288) cast x->x_bf.
__global__ __launch_bounds__(256) void transcribe_fused_kernel(
    const float4* __restrict__ seed, const float4* __restrict__ xin,
    const float* __restrict__ da, const float* __restrict__ db,
    short8* __restrict__ w_out, short8* __restrict__ x_out)
{
    const int b = blockIdx.x;
    short8 o;
    if (b < WBLOCKS) {
        int i = b * 256 + threadIdx.x;
        float4 u = seed[2 * i];
        float4 v = seed[2 * i + 1];
        u.x *= INV_2PI; u.y *= INV_2PI; u.z *= INV_2PI; u.w *= INV_2PI;
        v.x *= INV_2PI; v.y *= INV_2PI; v.z *= INV_2PI; v.w *= INV_2PI;
#pragma unroll
        for (int t = 0; t < NITER; t++) {
            float a = da[t], bc = db[t] * INV_2PI;
            step4(u, a, bc);
            step4(v, a, bc);
        }
        o[0] = (short)f2bf(u.x * TWO_PI); o[1] = (short)f2bf(u.y * TWO_PI);
        o[2] = (short)f2bf(u.z * TWO_PI); o[3] = (short)f2bf(u.w * TWO_PI);
        o[4] = (short)f2bf(v.x * TWO_PI); o[5] = (short)f2bf(v.y * TWO_PI);
        o[6] = (short)f2bf(v.z * TWO_PI); o[7] = (short)f2bf(v.w * TWO_PI);
        w_out[i] = o;
    } else {
        int i = (b - WBLOCKS) * 256 + threadIdx.x;
        float4 u = xin[2 * i];
        float4 v = xin[2 * i + 1];
        o[0] = (short)f2bf(u.x); o[1] = (short)f2bf(u.y);
        o[2] = (short)f2bf(u.z); o[3] = (short)f2bf(u.w);
        o[4] = (short)f2bf(v.x); o[5] = (short)f2bf(v.y);
        o[6] = (short)f2bf(v.z); o[7] = (short)f2bf(v.w);
        x_out[i] = o;
    }
}

// async 16B global -> LDS (per-lane global addr, linear wave-uniform LDS dest)
__device__ __forceinline__ void g2l16(const ushort* g, ushort* l) {
    __builtin_amdgcn_global_load_lds(
        (const __attribute__((address_space(1))) unsigned int*)g,
        (__attribute__((address_space(3))) unsigned int*)l, 16, 0, 0);
}

// ---------------------------------------------------------------------------
// GEMM: frozen at the round-2 form (74.5-74.9us, MfmaUtil ~37%, conflicts 0,
// FETCH 82MB).  Three schedule variants (counted-vmcnt ring, K-split,
// register ping-pong) all measured identical -> GEMM is at a structural
// plateau; this round targets the transcribe kernel instead.
// ---------------------------------------------------------------------------
#define BK     64
#define BM     256
#define BN     128
#define NT     (IN_F / BK)        // 64 K-tiles
#define ASLOT  (BM * BK)          // 16384 ushorts = 32 KiB
#define BSLOT  (BN * BK)          //  8192 ushorts = 16 KiB
#define LDS_BYTES (3 * (ASLOT + BSLOT) * 2)   // 147456 B = 144 KiB

__global__ __launch_bounds__(512, 2) void gemm_bt_kernel(
    const ushort* __restrict__ A,
    const ushort* __restrict__ B,
    const float* __restrict__ bias,
    float* __restrict__ C)
{
    extern __shared__ ushort lds[];
    ushort* As = lds;                  // [3][ASLOT]
    ushort* Bs = lds + 3 * ASLOT;      // [3][BSLOT]

    const int tid  = threadIdx.x;
    const int lane = tid & 63;
    const int wid  = tid >> 6;         // 0..7
    const int g    = wid >> 2;         // K-group: 0 -> k[0,32), 1 -> k[32,64)
    const int w2   = wid & 3;          // spatial wave 2x2
    const int wm   = (w2 >> 1) << 7;   // 0/128
    const int wn   = (w2 & 1) << 6;    // 0/64
    const int fm   = lane & 15;
    const int q    = lane >> 4;        // 0..3

    // XCD-aware swizzle, bn-stripes (verified: FETCH 139->82 MB)
    const int bid = blockIdx.x;
    const int jj  = bid >> 3;                  // 0..31
    const int bn  = (bid & 7) * 4 + (jj & 3);  // 0..31
    const int bm  = jj >> 2;                   // 0..7

    // staging: wave-instr covers 64 consecutive 16B chunks (8 rows x 8 segs);
    // lane = (row&7)*8 + pseg; global source segment = pseg ^ (row&7).
    const int gcol = (((lane & 7) ^ (lane >> 3)) << 3);

    const ushort* gA = A + (size_t)(bm * BM) * IN_F;
    const ushort* gB = B + (size_t)(bn * BN) * IN_F;

    floatx4 acc[8][4];
#pragma unroll
    for (int i = 0; i < 8; i++)
#pragma unroll
        for (int j = 0; j < 4; j++)
            acc[i][j] = (floatx4){0.f, 0.f, 0.f, 0.f};

    // 6 VMEM instrs per wave per tile (vmcnt counts these).
#define STAGE(k0v, sl)                                                        \
    {                                                                         \
        _Pragma("unroll")                                                     \
        for (int u = 0; u < 4; u++) {                                         \
            const int cb = ((u << 3) | wid) << 6;                             \
            const int r  = (cb >> 3) + (lane >> 3);                           \
            g2l16(gA + (size_t)r * IN_F + (k0v) + gcol,                       \
                  As + (sl) * ASLOT + cb * 8 + lane * 8);                     \
        }                                                                     \
        _Pragma("unroll")                                                     \
        for (int u = 0; u < 2; u++) {                                         \
            const int cb = ((u << 3) | wid) << 6;                             \
            const int r  = (cb >> 3) + (lane >> 3);                           \
            g2l16(gB + (size_t)r * IN_F + (k0v) + gcol,                       \
                  Bs + (sl) * BSLOT + cb * 8 + lane * 8);                     \
        }                                                                     \
    }

    // 12 x ds_read_b128: this wave's K-slice (= group g) of slot sl.
#define LOADFRAG(sl)                                                          \
    const int sa = (((q + 4 * g) & 7) ^ (fm & 7)) << 3;                       \
    _Pragma("unroll")                                                         \
    for (int i = 0; i < 8; i++)                                               \
        af[i] = *(const short8*)(As + (sl) * ASLOT + (wm + i * 16 + fm) * BK + sa); \
    _Pragma("unroll")                                                         \
    for (int j = 0; j < 4; j++)                                               \
        bf[j] = *(const short8*)(Bs + (sl) * BSLOT + (wn + j * 16 + fm) * BK + sa);

#define MFMA32()                                                              \
    __builtin_amdgcn_s_setprio(1);                                            \
    _Pragma("unroll")                                                         \
    for (int i = 0; i < 8; i++)                                               \
        _Pragma("unroll")                                                     \
        for (int j = 0; j < 4; j++)                                           \
            acc[i][j] = __builtin_amdgcn_mfma_f32_16x16x32_bf16(              \
                af[i], bf[j], acc[i][j], 0, 0, 0);                            \
    __builtin_amdgcn_s_setprio(0);

#define TILE_MAIN(vm, sl, k3)                                                 \
    {                                                                         \
        asm volatile("s_waitcnt vmcnt(" #vm ")" ::: "memory");                \
        __builtin_amdgcn_s_barrier();                                         \
        short8 af[8], bf[4];                                                  \
        LOADFRAG(sl);                                                         \
        asm volatile("s_waitcnt lgkmcnt(0)" ::: "memory");                    \
        __builtin_amdgcn_s_barrier();                                         \
        STAGE(k3, sl);                                                        \
        __builtin_amdgcn_sched_barrier(0);                                    \
        MFMA32();                                                             \
    }

#define TILE_TAIL(vm, sl)                                                     \
    {                                                                         \
        asm volatile("s_waitcnt vmcnt(" #vm ")" ::: "memory");                \
        __builtin_amdgcn_s_barrier();                                         \
        short8 af[8], bf[4];                                                  \
        LOADFRAG(sl);                                                         \
        MFMA32();                                                             \
    }

    // prologue: fill the 3-deep ring (18 loads/wave in flight)
    STAGE(0 * BK, 0);
    STAGE(1 * BK, 1);
    STAGE(2 * BK, 2);

    int st   = 0;
    int kpre = 3 * BK;
#pragma unroll 1
    for (int t = 0; t <= NT - 4; ++t) {        // t = 0..60, stages tiles 3..63
        TILE_MAIN(12, st, kpre);
        kpre += BK;
        st = (st == 2) ? 0 : st + 1;
    }
    // tail: tiles 61 (slot1), 62 (slot2), 63 (slot0); drain 12 -> 6 -> 0
    TILE_TAIL(12, 1);
    TILE_TAIL(6, 2);
    TILE_TAIL(0, 0);

#undef STAGE
#undef LOADFRAG
#undef MFMA32
#undef TILE_MAIN
#undef TILE_TAIL

    // K-split reduction: group1 parks partials in LDS, group0 sums + stores.
    __syncthreads();                       // all ring reads done before reuse
    floatx4* red = (floatx4*)lds;          // 128 KiB used of 144
    if (g == 1) {
#pragma unroll
        for (int i = 0; i < 8; i++)
#pragma unroll
            for (int j = 0; j < 4; j++)
                red[(size_t)(w2 * 32 + i * 4 + j) * 64 + lane] = acc[i][j];
    }
    __syncthreads();
    if (g == 0) {
        // epilogue: C/D layout col = lane&15, row = (lane>>4)*4 + reg  [m89]
        const int cn = lane & 15;
        const int cm = (lane >> 4) << 2;
        float bv[4];
#pragma unroll
        for (int j = 0; j < 4; j++)
            bv[j] = bias[bn * BN + wn + j * 16 + cn];
#pragma unroll
        for (int i = 0; i < 8; i++) {
#pragma unroll
            for (int j = 0; j < 4; j++) {
                floatx4 p = red[(size_t)(w2 * 32 + i * 4 + j) * 64 + lane];
#pragma unroll
                for (int r = 0; r < 4; r++) acc[i][j][r] += p[r];
            }
#pragma unroll
            for (int r = 0; r < 4; r++) {
                int m = bm * BM + wm + i * 16 + cm + r;
                float* crow = C + (size_t)m * OUT_F + bn * BN + wn + cn;
#pragma unroll
                for (int j = 0; j < 4; j++)
                    crow[j * 16] = acc[i][j][r] + bv[j];
            }
        }
    }
}

extern "C" void kernel_launch(void* const* d_in, const int* in_sizes, int n_in,
                              void* d_out, int out_size, void* d_ws, size_t ws_size,
                              hipStream_t stream) {
    const float* x    = (const float*)d_in[0];   // [2048, 4096]
    const float* seed = (const float*)d_in[1];   // [4096, 4096]
    const float* da   = (const float*)d_in[2];   // [20]
    const float* db   = (const float*)d_in[3];   // [20]
    const float* bias = (const float*)d_in[4];   // [4096]
    float* out        = (float*)d_out;           // [2048, 4096]

    ushort* w_bf = (ushort*)d_ws;                      // 32 MiB
    ushort* x_bf = w_bf + (size_t)OUT_F * IN_F;        // 16 MiB

    // allow 144 KiB dynamic LDS (one-time host-side attribute; not a stream op)
    static bool lds_attr_set = false;
    if (!lds_attr_set) {
        hipFuncSetAttribute(reinterpret_cast<const void*>(gemm_bt_kernel),
                            hipFuncAttributeMaxDynamicSharedMemorySize,
                            LDS_BYTES);
        lds_attr_set = true;
    }

    transcribe_fused_kernel<<<WBLOCKS + XBLOCKS, 256, 0, stream>>>(
        (const float4*)seed, (const float4*)x, da, db,
        (short8*)w_bf, (short8*)x_bf);

    gemm_bt_kernel<<<dim3(32 * 8), dim3(512), LDS_BYTES, stream>>>(
        x_bf, w_bf, bias, out);
}

// Round 5
// 208.720 us; speedup vs baseline: 1.2691x; 1.2691x over previous
//
#include <hip/hip_runtime.h>

typedef __attribute__((ext_vector_type(8))) short short8;
typedef __attribute__((ext_vector_type(4))) float floatx4;
typedef __attribute__((ext_vector_type(2))) float float2v;

#define TOKENS 2048
#define IN_F   4096
#define OUT_F  4096
#define NITER  20

#define INV_2PI 0.15915494309189535f
#define TWO_PI  6.283185307179586f

// round-to-nearest-even f32 -> bf16 bits
__device__ __forceinline__ unsigned short f2bf(float f) {
    unsigned int u = __builtin_bit_cast(unsigned int, f);
    u += 0x7fffu + ((u >> 16) & 1u);
    return (unsigned short)(u >> 16);
}

// ---------------------------------------------------------------------------
// Round-4 post-mortem: VALU-polynomial sin was 2.06x SLOWER than v_sin_f32
// (99us vs ~48us) -- v_sin is ~8-10cyc/wave-instr on the same issue pipe, so
// the poly's 22 VALU ops/sin lose.  REVERTED to hardware sin (revolution
// units).  The surrounding mul+fma are expressed on float2 so LLVM can emit
// v_pk_mul_f32 / v_pk_fma_f32 (CDNA packed dual-f32): halves the non-sin
// VALU cycles (640->320 of ~2400/wave).  If packing doesn't fire, codegen is
// identical to the round-3 baseline -- no downside.
// one fractal step in REVOLUTION units: v' = a*v + (b/2pi)*sin(2pi*v)
// ---------------------------------------------------------------------------
__device__ __forceinline__ void step2(float2v& v, float2v a2, float2v bc2) {
    float2v s;
    s.x = __builtin_amdgcn_sinf(v.x);
    s.y = __builtin_amdgcn_sinf(v.y);
    v = __builtin_elementwise_fma(bc2, s, v * a2);
}

#define WBLOCKS (OUT_F * IN_F / 8 / 256)   // 8192
#define XBLOCKS (TOKENS * IN_F / 8 / 256)  // 4096

// Fused: blocks [0,8192) transcribe seed->w_bf (20 iters); [8192,12288) cast x->x_bf.
__global__ __launch_bounds__(256) void transcribe_fused_kernel(
    const float4* __restrict__ seed, const float4* __restrict__ xin,
    const float* __restrict__ da, const float* __restrict__ db,
    short8* __restrict__ w_out, short8* __restrict__ x_out)
{
    const int b = blockIdx.x;
    short8 o;
    if (b < WBLOCKS) {
        int i = b * 256 + threadIdx.x;
        float4 U = seed[2 * i];
        float4 V = seed[2 * i + 1];
        float2v p0 = {U.x, U.y}, p1 = {U.z, U.w};
        float2v p2 = {V.x, V.y}, p3 = {V.z, V.w};
        const float2v kinv = {INV_2PI, INV_2PI};
        p0 *= kinv; p1 *= kinv; p2 *= kinv; p3 *= kinv;   // v_pk_mul_f32
#pragma unroll
        for (int t = 0; t < NITER; t++) {
            float a = da[t], bc = db[t] * INV_2PI;
            float2v a2 = {a, a}, bc2 = {bc, bc};
            step2(p0, a2, bc2);
            step2(p1, a2, bc2);
            step2(p2, a2, bc2);
            step2(p3, a2, bc2);
        }
        o[0] = (short)f2bf(p0.x * TWO_PI); o[1] = (short)f2bf(p0.y * TWO_PI);
        o[2] = (short)f2bf(p1.x * TWO_PI); o[3] = (short)f2bf(p1.y * TWO_PI);
        o[4] = (short)f2bf(p2.x * TWO_PI); o[5] = (short)f2bf(p2.y * TWO_PI);
        o[6] = (short)f2bf(p3.x * TWO_PI); o[7] = (short)f2bf(p3.y * TWO_PI);
        w_out[i] = o;
    } else {
        int i = (b - WBLOCKS) * 256 + threadIdx.x;
        float4 u = xin[2 * i];
        float4 v = xin[2 * i + 1];
        o[0] = (short)f2bf(u.x); o[1] = (short)f2bf(u.y);
        o[2] = (short)f2bf(u.z); o[3] = (short)f2bf(u.w);
        o[4] = (short)f2bf(v.x); o[5] = (short)f2bf(v.y);
        o[6] = (short)f2bf(v.z); o[7] = (short)f2bf(v.w);
        x_out[i] = o;
    }
}

// async 16B global -> LDS (per-lane global addr, linear wave-uniform LDS dest)
__device__ __forceinline__ void g2l16(const ushort* g, ushort* l) {
    __builtin_amdgcn_global_load_lds(
        (const __attribute__((address_space(1))) unsigned int*)g,
        (__attribute__((address_space(3))) unsigned int*)l, 16, 0, 0);
}

// ---------------------------------------------------------------------------
// GEMM: FROZEN at the round-2 form (74.5-74.9us = ~910 TF, MfmaUtil ~37%,
// conflicts 0, FETCH 82MB).  Three structurally different schedules
// (counted-vmcnt ring / K-split / register ping-pong) measured identical ->
// structural plateau for this tile class; do not touch without new evidence.
// ---------------------------------------------------------------------------
#define BK     64
#define BM     256
#define BN     128
#define NT     (IN_F / BK)        // 64 K-tiles
#define ASLOT  (BM * BK)          // 16384 ushorts = 32 KiB
#define BSLOT  (BN * BK)          //  8192 ushorts = 16 KiB
#define LDS_BYTES (3 * (ASLOT + BSLOT) * 2)   // 147456 B = 144 KiB

__global__ __launch_bounds__(512, 2) void gemm_bt_kernel(
    const ushort* __restrict__ A,
    const ushort* __restrict__ B,
    const float* __restrict__ bias,
    float* __restrict__ C)
{
    extern __shared__ ushort lds[];
    ushort* As = lds;                  // [3][ASLOT]
    ushort* Bs = lds + 3 * ASLOT;      // [3][BSLOT]

    const int tid  = threadIdx.x;
    const int lane = tid & 63;
    const int wid  = tid >> 6;         // 0..7
    const int g    = wid >> 2;         // K-group: 0 -> k[0,32), 1 -> k[32,64)
    const int w2   = wid & 3;          // spatial wave 2x2
    const int wm   = (w2 >> 1) << 7;   // 0/128
    const int wn   = (w2 & 1) << 6;    // 0/64
    const int fm   = lane & 15;
    const int q    = lane >> 4;        // 0..3

    // XCD-aware swizzle, bn-stripes (verified: FETCH 139->82 MB)
    const int bid = blockIdx.x;
    const int jj  = bid >> 3;                  // 0..31
    const int bn  = (bid & 7) * 4 + (jj & 3);  // 0..31
    const int bm  = jj >> 2;                   // 0..7

    // staging: wave-instr covers 64 consecutive 16B chunks (8 rows x 8 segs);
    // lane = (row&7)*8 + pseg; global source segment = pseg ^ (row&7).
    const int gcol = (((lane & 7) ^ (lane >> 3)) << 3);

    const ushort* gA = A + (size_t)(bm * BM) * IN_F;
    const ushort* gB = B + (size_t)(bn * BN) * IN_F;

    floatx4 acc[8][4];
#pragma unroll
    for (int i = 0; i < 8; i++)
#pragma unroll
        for (int j = 0; j < 4; j++)
            acc[i][j] = (floatx4){0.f, 0.f, 0.f, 0.f};

    // 6 VMEM instrs per wave per tile (vmcnt counts these).
#define STAGE(k0v, sl)                                                        \
    {                                                                         \
        _Pragma("unroll")                                                     \
        for (int u = 0; u < 4; u++) {                                         \
            const int cb = ((u << 3) | wid) << 6;                             \
            const int r  = (cb >> 3) + (lane >> 3);                           \
            g2l16(gA + (size_t)r * IN_F + (k0v) + gcol,                       \
                  As + (sl) * ASLOT + cb * 8 + lane * 8);                     \
        }                                                                     \
        _Pragma("unroll")                                                     \
        for (int u = 0; u < 2; u++) {                                         \
            const int cb = ((u << 3) | wid) << 6;                             \
            const int r  = (cb >> 3) + (lane >> 3);                           \
            g2l16(gB + (size_t)r * IN_F + (k0v) + gcol,                       \
                  Bs + (sl) * BSLOT + cb * 8 + lane * 8);                     \
        }                                                                     \
    }

    // 12 x ds_read_b128: this wave's K-slice (= group g) of slot sl.
#define LOADFRAG(sl)                                                          \
    const int sa = (((q + 4 * g) & 7) ^ (fm & 7)) << 3;                       \
    _Pragma("unroll")                                                         \
    for (int i = 0; i < 8; i++)                                               \
        af[i] = *(const short8*)(As + (sl) * ASLOT + (wm + i * 16 + fm) * BK + sa); \
    _Pragma("unroll")                                                         \
    for (int j = 0; j < 4; j++)                                               \
        bf[j] = *(const short8*)(Bs + (sl) * BSLOT + (wn + j * 16 + fm) * BK + sa);

#define MFMA32()                                                              \
    __builtin_amdgcn_s_setprio(1);                                            \
    _Pragma("unroll")                                                         \
    for (int i = 0; i < 8; i++)                                               \
        _Pragma("unroll")                                                     \
        for (int j = 0; j < 4; j++)                                           \
            acc[i][j] = __builtin_amdgcn_mfma_f32_16x16x32_bf16(              \
                af[i], bf[j], acc[i][j], 0, 0, 0);                            \
    __builtin_amdgcn_s_setprio(0);

#define TILE_MAIN(vm, sl, k3)                                                 \
    {                                                                         \
        asm volatile("s_waitcnt vmcnt(" #vm ")" ::: "memory");                \
        __builtin_amdgcn_s_barrier();                                         \
        short8 af[8], bf[4];                                                  \
        LOADFRAG(sl);                                                         \
        asm volatile("s_waitcnt lgkmcnt(0)" ::: "memory");                    \
        __builtin_amdgcn_s_barrier();                                         \
        STAGE(k3, sl);                                                        \
        __builtin_amdgcn_sched_barrier(0);                                    \
        MFMA32();                                                             \
    }

#define TILE_TAIL(vm, sl)                                                     \
    {                                                                         \
        asm volatile("s_waitcnt vmcnt(" #vm ")" ::: "memory");                \
        __builtin_amdgcn_s_barrier();                                         \
        short8 af[8], bf[4];                                                  \
        LOADFRAG(sl);                                                         \
        MFMA32();                                                             \
    }

    // prologue: fill the 3-deep ring (18 loads/wave in flight)
    STAGE(0 * BK, 0);
    STAGE(1 * BK, 1);
    STAGE(2 * BK, 2);

    int st   = 0;
    int kpre = 3 * BK;
#pragma unroll 1
    for (int t = 0; t <= NT - 4; ++t) {        // t = 0..60, stages tiles 3..63
        TILE_MAIN(12, st, kpre);
        kpre += BK;
        st = (st == 2) ? 0 : st + 1;
    }
    // tail: tiles 61 (slot1), 62 (slot2), 63 (slot0); drain 12 -> 6 -> 0
    TILE_TAIL(12, 1);
    TILE_TAIL(6, 2);
    TILE_TAIL(0, 0);

#undef STAGE
#undef LOADFRAG
#undef MFMA32
#undef TILE_MAIN
#undef TILE_TAIL

    // K-split reduction: group1 parks partials in LDS, group0 sums + stores.
    __syncthreads();                       // all ring reads done before reuse
    floatx4* red = (floatx4*)lds;          // 128 KiB used of 144
    if (g == 1) {
#pragma unroll
        for (int i = 0; i < 8; i++)
#pragma unroll
            for (int j = 0; j < 4; j++)
                red[(size_t)(w2 * 32 + i * 4 + j) * 64 + lane] = acc[i][j];
    }
    __syncthreads();
    if (g == 0) {
        // epilogue: C/D layout col = lane&15, row = (lane>>4)*4 + reg  [m89]
        const int cn = lane & 15;
        const int cm = (lane >> 4) << 2;
        float bv[4];
#pragma unroll
        for (int j = 0; j < 4; j++)
            bv[j] = bias[bn * BN + wn + j * 16 + cn];
#pragma unroll
        for (int i = 0; i < 8; i++) {
#pragma unroll
            for (int j = 0; j < 4; j++) {
                floatx4 p = red[(size_t)(w2 * 32 + i * 4 + j) * 64 + lane];
#pragma unroll
                for (int r = 0; r < 4; r++) acc[i][j][r] += p[r];
            }
#pragma unroll
            for (int r = 0; r < 4; r++) {
                int m = bm * BM + wm + i * 16 + cm + r;
                float* crow = C + (size_t)m * OUT_F + bn * BN + wn + cn;
#pragma unroll
                for (int j = 0; j < 4; j++)
                    crow[j * 16] = acc[i][j][r] + bv[j];
            }
        }
    }
}

extern "C" void kernel_launch(void* const* d_in, const int* in_sizes, int n_in,
                              void* d_out, int out_size, void* d_ws, size_t ws_size,
                              hipStream_t stream) {
    const float* x    = (const float*)d_in[0];   // [2048, 4096]
    const float* seed = (const float*)d_in[1];   // [4096, 4096]
    const float* da   = (const float*)d_in[2];   // [20]
    const float* db   = (const float*)d_in[3];   // [20]
    const float* bias = (const float*)d_in[4];   // [4096]
    float* out        = (float*)d_out;           // [2048, 4096]

    ushort* w_bf = (ushort*)d_ws;                      // 32 MiB
    ushort* x_bf = w_bf + (size_t)OUT_F * IN_F;        // 16 MiB

    // allow 144 KiB dynamic LDS (one-time host-side attribute; not a stream op)
    static bool lds_attr_set = false;
    if (!lds_attr_set) {
        hipFuncSetAttribute(reinterpret_cast<const void*>(gemm_bt_kernel),
                            hipFuncAttributeMaxDynamicSharedMemorySize,
                            LDS_BYTES);
        lds_attr_set = true;
    }

    transcribe_fused_kernel<<<WBLOCKS + XBLOCKS, 256, 0, stream>>>(
        (const float4*)seed, (const float4*)x, da, db,
        (short8*)w_bf, (short8*)x_bf);

    gemm_bt_kernel<<<dim3(32 * 8), dim3(512), LDS_BYTES, stream>>>(
        x_bf, w_bf, bias, out);
}